// Round 6
// baseline (332.822 us; speedup 1.0000x reference)
//
#include <hip/hip_runtime.h>
#include <hip/hip_bf16.h>
#include <cstdint>

// Problem constants (reference: N=8192, D=2048, M=512, E=4, SCALE=1)
#define N_TOK  8192
#define DDIM   2048
#define MDIM   512
#define NEXP   4
#define NSPLIT 4          // gemm1 K-split
#define LDSW   72         // LDS row stride (bf16 elems): 144B = 36 banks -> 2-way (free)

typedef __bf16 bf16x4 __attribute__((ext_vector_type(4)));
typedef __bf16 bf16x8 __attribute__((ext_vector_type(8)));
typedef float  f32x4  __attribute__((ext_vector_type(4)));

// ---------------------------------------------------------------------------
// Device-global scratch (fully rewritten every call; no ws_size dependence).
// ---------------------------------------------------------------------------
__device__ int g_counts[NEXP];
__device__ int g_idx[NEXP * N_TOK];
__device__ int g_exp[N_TOK];
__device__ float g_H32[NSPLIT][(size_t)N_TOK * MDIM];   // 4 x 16 MB split-K partials
__device__ __hip_bfloat16 g_H[(size_t)N_TOK * MDIM];    // 8 MB hidden acts (bf16)

__global__ void zero_counts_kernel() {
    if (threadIdx.x < NEXP) g_counts[threadIdx.x] = 0;
}

// ---------------------------------------------------------------------------
// Bucket tokens by expert — wave-aggregated atomics; also records token->expert.
// ---------------------------------------------------------------------------
__global__ void bucket_kernel(const void* __restrict__ domv) {
    const int i    = blockIdx.x * blockDim.x + threadIdx.x;
    const int lane = threadIdx.x & 63;

    const long long* d64 = (const long long*)domv;
    long long probe = d64[lane];
    bool mode64 = (__ballot(probe >= 0 && probe < NEXP) == ~0ull);

    const int e = mode64 ? (int)d64[i] : ((const int*)domv)[i];
    g_exp[i] = e;

#pragma unroll
    for (int ex = 0; ex < NEXP; ++ex) {
        unsigned long long m = __ballot(e == ex);
        if (m == 0) continue;
        int cnt    = __popcll(m);
        int leader = __ffsll((long long)m) - 1;
        int base   = 0;
        if (lane == leader) base = atomicAdd(&g_counts[ex], cnt);
        base = __shfl(base, leader);
        if (e == ex) {
            int prefix = __popcll(m & ((1ull << lane) - 1ull));
            g_idx[ex * N_TOK + base + prefix] = i;
        }
    }
}

__device__ __forceinline__ bf16x4 cvt4(f32x4 v) {
    bf16x4 r;
    r[0] = (__bf16)v[0]; r[1] = (__bf16)v[1];
    r[2] = (__bf16)v[2]; r[3] = (__bf16)v[3];
    return r;
}
__device__ __forceinline__ f32x4 mfma16(bf16x8 a, bf16x8 b, f32x4 c) {
    return __builtin_amdgcn_mfma_f32_16x16x32_bf16(a, b, c, 0, 0, 0);
}

// ---------------------------------------------------------------------------
// GEMM1 split-K: partial[ks][t, col] = sum_{k in slice} x[t,k] * W1[e,col,k]
// Tile 64x64, BK=64 (8 iters of 8 MFMA), 4 waves 2x2. Plain fp32 stores.
// ---------------------------------------------------------------------------
__global__ __launch_bounds__(256)
void gemm1_kernel(const float* __restrict__ x, const float* __restrict__ W1) {
    const int rt = blockIdx.x;
    const int ct = blockIdx.y;
    const int e  = blockIdx.z >> 2;
    const int ks = blockIdx.z & 3;
    const int cnt = g_counts[e];
    if (rt * 64 >= cnt) return;
    const int kbase = ks * (DDIM / NSPLIT);          // 512-wide K slice

    __shared__ __align__(16) __hip_bfloat16 sA[64 * LDSW];
    __shared__ __align__(16) __hip_bfloat16 sB[64 * LDSW];
    __shared__ int sTok[64];

    const int tid = threadIdx.x;
    if (tid < 64) {
        int slot = rt * 64 + tid;
        sTok[tid] = g_idx[e * N_TOK + (slot < cnt ? slot : cnt - 1)];
    }
    __syncthreads();

    // staging: chunk c = tid + 256p (p=0..3): row = (tid>>4)+16p, col = (tid&15)*4
    const int srow = tid >> 4;
    const int scol = (tid & 15) * 4;
    const float* gA[4]; const float* gB[4];
#pragma unroll
    for (int p = 0; p < 4; ++p) {
        const int row = srow + 16 * p;
        gA[p] = x  + (size_t)sTok[row] * DDIM + kbase + scol;
        gB[p] = W1 + ((size_t)e * MDIM + (size_t)(ct * 64 + row)) * DDIM + kbase + scol;
    }

    const int wave = tid >> 6, lane = tid & 63;
    const int wm = (wave >> 1) * 32, wn = (wave & 1) * 32;
    const int frow = lane & 15, fk = (lane >> 4) * 8;

    f32x4 acc[2][2] = {};
    f32x4 ra[4], rb[4];

    auto load_tile = [&](int k0) {
#pragma unroll
        for (int p = 0; p < 4; ++p) {
            ra[p] = *(const f32x4*)(gA[p] + k0);
            rb[p] = *(const f32x4*)(gB[p] + k0);
        }
    };
    auto store_tile = [&]() {
#pragma unroll
        for (int p = 0; p < 4; ++p) {
            const int row = srow + 16 * p;
            *(bf16x4*)&sA[row * LDSW + scol] = cvt4(ra[p]);
            *(bf16x4*)&sB[row * LDSW + scol] = cvt4(rb[p]);
        }
    };

    load_tile(0);
    for (int k0 = 0; k0 < DDIM / NSPLIT; k0 += 64) {
        __syncthreads();
        store_tile();
        __syncthreads();
        if (k0 + 64 < DDIM / NSPLIT) load_tile(k0 + 64);
#pragma unroll
        for (int h = 0; h < 2; ++h) {
            const __hip_bfloat16* ap = &sA[frow * LDSW + h * 32 + fk];
            const __hip_bfloat16* bp = &sB[frow * LDSW + h * 32 + fk];
            bf16x8 a0 = *(const bf16x8*)(ap + wm * LDSW);
            bf16x8 a1 = *(const bf16x8*)(ap + (wm + 16) * LDSW);
            bf16x8 b0 = *(const bf16x8*)(bp + wn * LDSW);
            bf16x8 b1 = *(const bf16x8*)(bp + (wn + 16) * LDSW);
            acc[0][0] = mfma16(a0, b0, acc[0][0]);
            acc[0][1] = mfma16(a0, b1, acc[0][1]);
            acc[1][0] = mfma16(a1, b0, acc[1][0]);
            acc[1][1] = mfma16(a1, b1, acc[1][1]);
        }
    }

    // epilogue: plain fp32 partial stores. C/D layout col=lane&15, row=(lane>>4)*4+r
    const int crow = (lane >> 4) * 4, ccol = lane & 15;
    float* Hp = g_H32[ks];
#pragma unroll
    for (int i = 0; i < 2; ++i) {
        const int rl = wm + i * 16 + crow;
#pragma unroll
        for (int r = 0; r < 4; ++r) {
            const int slot = rt * 64 + rl + r;
            if (slot < cnt) {
                const int t = sTok[rl + r];
#pragma unroll
                for (int j = 0; j < 2; ++j) {
                    const int col = ct * 64 + wn + j * 16 + ccol;
                    Hp[(size_t)t * MDIM + col] = acc[i][j][r];
                }
            }
        }
    }
}

// ---------------------------------------------------------------------------
// Reduce split-K partials + bias + ReLU + cvt -> g_H (bf16)
// ---------------------------------------------------------------------------
__global__ __launch_bounds__(256)
void relu_cvt_kernel(const float* __restrict__ b1) {
    const int idx = (blockIdx.x * 256 + threadIdx.x) * 4;
    const int t = idx >> 9;            // / MDIM
    const int m = idx & (MDIM - 1);
    f32x4 s = *(const f32x4*)&g_H32[0][idx];
#pragma unroll
    for (int ks = 1; ks < NSPLIT; ++ks) s += *(const f32x4*)&g_H32[ks][idx];
    const int e = g_exp[t];
    f32x4 b = *(const f32x4*)&b1[e * MDIM + m];
    bf16x4 o;
#pragma unroll
    for (int q = 0; q < 4; ++q) o[q] = (__bf16)fmaxf(s[q] + b[q], 0.0f);
    *(bf16x4*)&g_H[idx] = o;
}

// ---------------------------------------------------------------------------
// GEMM2: out[t,col] = x[t,col] + sum_k H[t,k]*W2[e,col,k] + b2[e,col]
// Tile 64x64, BK=64, K=512 -> 8 iters.
// ---------------------------------------------------------------------------
__global__ __launch_bounds__(256)
void gemm2_kernel(const float* __restrict__ x, const float* __restrict__ W2,
                  const float* __restrict__ b2, float* __restrict__ out) {
    const int rt = blockIdx.x;
    const int ct = blockIdx.y;
    const int e  = blockIdx.z;
    const int cnt = g_counts[e];
    if (rt * 64 >= cnt) return;

    __shared__ __align__(16) __hip_bfloat16 sA[64 * LDSW];
    __shared__ __align__(16) __hip_bfloat16 sB[64 * LDSW];
    __shared__ int sTok[64];

    const int tid = threadIdx.x;
    if (tid < 64) {
        int slot = rt * 64 + tid;
        sTok[tid] = g_idx[e * N_TOK + (slot < cnt ? slot : cnt - 1)];
    }
    __syncthreads();

    // A staging (bf16): chunk c = tid + 256p (p=0..1): row = c>>3, col8 = (c&7)*8
    const int arow = tid >> 3;               // 0..31
    const int acol = (tid & 7) * 8;
    const __hip_bfloat16* gA0 = g_H + (size_t)sTok[arow] * MDIM + acol;
    const __hip_bfloat16* gA1 = g_H + (size_t)sTok[arow + 32] * MDIM + acol;
    // B staging (fp32): as gemm1
    const int srow = tid >> 4;
    const int scol = (tid & 15) * 4;
    const float* gB[4];
#pragma unroll
    for (int p = 0; p < 4; ++p)
        gB[p] = W2 + ((size_t)e * DDIM + (size_t)(ct * 64 + srow + 16 * p)) * MDIM + scol;

    const int wave = tid >> 6, lane = tid & 63;
    const int wm = (wave >> 1) * 32, wn = (wave & 1) * 32;
    const int frow = lane & 15, fk = (lane >> 4) * 8;

    f32x4 acc[2][2] = {};
    bf16x8 ra0, ra1;
    f32x4 rb[4];

    auto load_tile = [&](int k0) {
        ra0 = *(const bf16x8*)(gA0 + k0);
        ra1 = *(const bf16x8*)(gA1 + k0);
#pragma unroll
        for (int p = 0; p < 4; ++p) rb[p] = *(const f32x4*)(gB[p] + k0);
    };
    auto store_tile = [&]() {
        *(bf16x8*)&sA[arow * LDSW + acol]        = ra0;
        *(bf16x8*)&sA[(arow + 32) * LDSW + acol] = ra1;
#pragma unroll
        for (int p = 0; p < 4; ++p)
            *(bf16x4*)&sB[(srow + 16 * p) * LDSW + scol] = cvt4(rb[p]);
    };

    load_tile(0);
    for (int k0 = 0; k0 < MDIM; k0 += 64) {
        __syncthreads();
        store_tile();
        __syncthreads();
        if (k0 + 64 < MDIM) load_tile(k0 + 64);
#pragma unroll
        for (int h = 0; h < 2; ++h) {
            const __hip_bfloat16* ap = &sA[frow * LDSW + h * 32 + fk];
            const __hip_bfloat16* bp = &sB[frow * LDSW + h * 32 + fk];
            bf16x8 a0 = *(const bf16x8*)(ap + wm * LDSW);
            bf16x8 a1 = *(const bf16x8*)(ap + (wm + 16) * LDSW);
            bf16x8 b0 = *(const bf16x8*)(bp + wn * LDSW);
            bf16x8 b1 = *(const bf16x8*)(bp + (wn + 16) * LDSW);
            acc[0][0] = mfma16(a0, b0, acc[0][0]);
            acc[0][1] = mfma16(a0, b1, acc[0][1]);
            acc[1][0] = mfma16(a1, b0, acc[1][0]);
            acc[1][1] = mfma16(a1, b1, acc[1][1]);
        }
    }

    const int crow = (lane >> 4) * 4, ccol = lane & 15;
#pragma unroll
    for (int j = 0; j < 2; ++j) {
        const int col = ct * 64 + wn + j * 16 + ccol;
        const float bv = b2[(size_t)e * DDIM + col];
#pragma unroll
        for (int i = 0; i < 2; ++i) {
            const int rl = wm + i * 16 + crow;
#pragma unroll
            for (int r = 0; r < 4; ++r) {
                const int slot = rt * 64 + rl + r;
                if (slot < cnt) {
                    const int t = sTok[rl + r];
                    out[(size_t)t * DDIM + col] =
                        acc[i][j][r] + bv + x[(size_t)t * DDIM + col];
                }
            }
        }
    }
}

extern "C" void kernel_launch(void* const* d_in, const int* in_sizes, int n_in,
                              void* d_out, int out_size, void* d_ws, size_t ws_size,
                              hipStream_t stream) {
    const float* x  = (const float*)d_in[0];
    const void*  dm = d_in[1];
    const float* W1 = (const float*)d_in[2];
    const float* b1 = (const float*)d_in[3];
    const float* W2 = (const float*)d_in[4];
    const float* b2 = (const float*)d_in[5];
    float* out = (float*)d_out;

    zero_counts_kernel<<<1, 64, 0, stream>>>();
    bucket_kernel<<<N_TOK / 256, 256, 0, stream>>>(dm);

    // GEMM1 split-K: partials over 4 K-slices of 512
    gemm1_kernel<<<dim3(N_TOK / 64, MDIM / 64, NEXP * NSPLIT), 256, 0, stream>>>(x, W1);

    // reduce + bias + ReLU + cvt -> g_H
    relu_cvt_kernel<<<(N_TOK * MDIM / 4) / 256, 256, 0, stream>>>(b1);

    // GEMM2: out = x + H @ W2[e]^T + b2[e]
    gemm2_kernel<<<dim3(N_TOK / 64, DDIM / 64, NEXP), 256, 0, stream>>>(x, W2, b2, out);
}